// Round 1
// baseline (734.631 us; speedup 1.0000x reference)
//
#include <hip/hip_runtime.h>
#include <math.h>

// Problem constants (from reference)
#define N_SAMP 200000
#define D_     128
#define T_     8
#define P_     2000
#define NP_    9
#define H_     2048

// Workspace layout (bytes). fingerprint is finalized IN PLACE over pt_sum
// (identical flat index layout: (p*T+t)*D+d == p*1024 + t*128 + d).
#define OFF_PTSUM   0
#define SZ_PTSUM    (16000*128*4)            // 8,192,000
#define OFF_PTCNT   (OFF_PTSUM + SZ_PTSUM)   // 8,192,000
#define SZ_PTCNT    (16000*4)                // 64,000
#define OFF_FIRST   (OFF_PTCNT + SZ_PTCNT)   // 8,256,000
#define SZ_FIRST    (P_*4)                   // 8,000
#define OFF_TMEAN   8264192                  // 256-aligned
#define SZ_TMEAN    (T_*D_*4)                // 4,096
#define OFF_H1      8268288                  // 256-aligned
#define SZ_H1       (P_*H_*4)                // 16,384,000
#define OFF_H2      (OFF_H1 + SZ_H1)         // 24,652,288
// total ~41.0 MB

// ---------------------------------------------------------------------------
// Kernel 1: scatter-reduce. One wave (64 lanes) per sample row.
// Valid rows (~25%) scatter 128 f32 atomicAdds into pt_sum, 1 into pt_cnt,
// 1 atomicMin into first[patient]. Invalid rows skip the motion_z read.
// ---------------------------------------------------------------------------
__global__ __launch_bounds__(256) void scatter_pt(
    const float* __restrict__ motion_z, const int* __restrict__ tasks,
    const int* __restrict__ tmask, const int* __restrict__ pids,
    const int* __restrict__ pmask, float* __restrict__ pt_sum,
    float* __restrict__ pt_cnt, int* __restrict__ first)
{
    int wid  = (blockIdx.x * blockDim.x + threadIdx.x) >> 6;   // sample row
    int lane = threadIdx.x & 63;
    if (wid >= N_SAMP) return;
    int tm = tmask[wid], pm = pmask[wid];
    if (tm != 1 || pm != 1) return;                            // wave-uniform
    int t = tasks[wid], p = pids[wid];
    int seg = p * T_ + t;
    if (lane == 0) {
        atomicAdd(&pt_cnt[seg], 1.0f);
        atomicMin(&first[p], wid);
    }
    float2 v = *(const float2*)&motion_z[(size_t)wid * D_ + lane * 2];
    atomicAdd(&pt_sum[seg * D_ + lane * 2 + 0], v.x);
    atomicAdd(&pt_sum[seg * D_ + lane * 2 + 1], v.y);
}

// ---------------------------------------------------------------------------
// Kernel 2: task_mean[t][d] = sum_p pt_sum[p*T+t][d] / max(sum_p pt_cnt,1)
// 1024 threads; pt_sum is L2-resident (8 MB) after the scatter pass.
// ---------------------------------------------------------------------------
__global__ __launch_bounds__(256) void task_mean_k(
    const float* __restrict__ pt_sum, const float* __restrict__ pt_cnt,
    float* __restrict__ tmean)
{
    int tid = blockIdx.x * blockDim.x + threadIdx.x;
    if (tid >= T_ * D_) return;
    int t = tid >> 7, d = tid & 127;
    float s = 0.f, c = 0.f;
    for (int p = 0; p < P_; ++p) {
        s += pt_sum[(size_t)(p * T_ + t) * D_ + d];
        c += pt_cnt[p * T_ + t];
    }
    tmean[tid] = s / fmaxf(c, 1.0f);
}

// ---------------------------------------------------------------------------
// Kernel 3: finalize fingerprint IN PLACE: pt_sum[e] = cnt>0 ? sum/cnt : tmean
// ---------------------------------------------------------------------------
__global__ __launch_bounds__(256) void finalize_fp(
    float* __restrict__ pt_sum, const float* __restrict__ pt_cnt,
    const float* __restrict__ tmean)
{
    int e = blockIdx.x * blockDim.x + threadIdx.x;
    if (e >= 16000 * D_) return;
    int seg = e >> 7;                         // p*T+t
    int td  = ((seg & 7) << 7) | (e & 127);   // t*128+d
    float c = pt_cnt[seg];
    pt_sum[e] = (c > 0.f) ? pt_sum[e] / c : tmean[td];
}

// ---------------------------------------------------------------------------
// Kernel 4: gather first-valid pheno row per patient.
// ---------------------------------------------------------------------------
__global__ void gather_phenos(const int* __restrict__ first,
                              const float* __restrict__ phenos,
                              float* __restrict__ up)
{
    int e = blockIdx.x * blockDim.x + threadIdx.x;
    if (e >= P_ * NP_) return;
    int p = e / NP_, j = e - p * NP_;
    int idx = first[p];
    if (idx > N_SAMP - 1) idx = N_SAMP - 1;   // clip (handles 0x7f7f7f7f init)
    up[e] = phenos[(size_t)idx * NP_ + j];
}

// ---------------------------------------------------------------------------
// Kernel 5: fp32 tiled GEMM, C[M,N] = act(A[M,K] @ B[K,N] + bias), row-major.
// BM=64 BN=128 BK=16, 256 threads, per-thread 4x8 register tile.
// N, K divisible by tile dims (N=2048, K=1024/2048); only M (2000) is ragged.
// ---------------------------------------------------------------------------
#define BM 64
#define BN 128
#define BK 16
__global__ __launch_bounds__(256) void gemm_bias_act(
    const float* __restrict__ A, const float* __restrict__ B,
    const float* __restrict__ bias, float* __restrict__ C,
    int M, int N, int K, int relu)
{
    __shared__ float As[BK][BM + 4];   // stride 68: 16B-aligned float4 reads, 2-way banks
    __shared__ float Bs[BK][BN];
    int tid = threadIdx.x;
    int tx = tid & 15;                 // col group: 8 cols each
    int ty = tid >> 4;                 // row group: 4 rows each
    int row0 = blockIdx.y * BM, col0 = blockIdx.x * BN;

    int arow = tid >> 2;               // 0..63
    int acol = (tid & 3) * 4;          // 0,4,8,12
    int b0r = tid >> 5;                // 0..7
    int b0c = (tid & 31) * 4;
    int b1r = b0r + 8;

    float acc[4][8] = {};
    int nk = K / BK;
    for (int kt = 0; kt < nk; ++kt) {
        int k0 = kt * BK;
        float4 av = (row0 + arow < M)
            ? *(const float4*)&A[(size_t)(row0 + arow) * K + k0 + acol]
            : make_float4(0.f, 0.f, 0.f, 0.f);
        float4 bv0 = *(const float4*)&B[(size_t)(k0 + b0r) * N + col0 + b0c];
        float4 bv1 = *(const float4*)&B[(size_t)(k0 + b1r) * N + col0 + b0c];
        __syncthreads();               // previous iter's LDS reads done
        As[acol + 0][arow] = av.x;
        As[acol + 1][arow] = av.y;
        As[acol + 2][arow] = av.z;
        As[acol + 3][arow] = av.w;
        *(float4*)&Bs[b0r][b0c] = bv0;
        *(float4*)&Bs[b1r][b0c] = bv1;
        __syncthreads();
#pragma unroll
        for (int k = 0; k < BK; ++k) {
            float4 a  = *(const float4*)&As[k][ty * 4];
            float4 bb0 = *(const float4*)&Bs[k][tx * 8];
            float4 bb1 = *(const float4*)&Bs[k][tx * 8 + 4];
            float ar[4] = {a.x, a.y, a.z, a.w};
            float br[8] = {bb0.x, bb0.y, bb0.z, bb0.w, bb1.x, bb1.y, bb1.z, bb1.w};
#pragma unroll
            for (int i = 0; i < 4; ++i)
#pragma unroll
                for (int j = 0; j < 8; ++j)
                    acc[i][j] = fmaf(ar[i], br[j], acc[i][j]);
        }
    }
    // epilogue
    float4 bia0 = *(const float4*)&bias[col0 + tx * 8];
    float4 bia1 = *(const float4*)&bias[col0 + tx * 8 + 4];
    float bi[8] = {bia0.x, bia0.y, bia0.z, bia0.w, bia1.x, bia1.y, bia1.z, bia1.w};
#pragma unroll
    for (int i = 0; i < 4; ++i) {
        int r = row0 + ty * 4 + i;
        if (r >= M) continue;
        float v[8];
#pragma unroll
        for (int j = 0; j < 8; ++j) {
            float x = acc[i][j] + bi[j];
            v[j] = relu ? fmaxf(x, 0.f) : x;
        }
        *(float4*)&C[(size_t)r * N + col0 + tx * 8]     = make_float4(v[0], v[1], v[2], v[3]);
        *(float4*)&C[(size_t)r * N + col0 + tx * 8 + 4] = make_float4(v[4], v[5], v[6], v[7]);
    }
}

// ---------------------------------------------------------------------------
// Kernel 6: head GEMM [2000,2048]@[2048,9] + b3 -> latent; out = sigmoid.
// One wave per row; 9 accumulators per lane; butterfly reduce.
// ---------------------------------------------------------------------------
__global__ __launch_bounds__(256) void out_head(
    const float* __restrict__ h2, const float* __restrict__ W3,
    const float* __restrict__ b3, float* __restrict__ out,
    float* __restrict__ latent)
{
    int wid  = (blockIdx.x * blockDim.x + threadIdx.x) >> 6;
    int lane = threadIdx.x & 63;
    if (wid >= P_) return;
    const float* hrow = h2 + (size_t)wid * H_;
    float acc[NP_] = {};
    for (int k = lane; k < H_; k += 64) {
        float h = hrow[k];
        const float* wr = W3 + (size_t)k * NP_;
#pragma unroll
        for (int j = 0; j < NP_; ++j) acc[j] = fmaf(h, wr[j], acc[j]);
    }
#pragma unroll
    for (int off = 32; off > 0; off >>= 1)
#pragma unroll
        for (int j = 0; j < NP_; ++j) acc[j] += __shfl_down(acc[j], off);
    if (lane == 0) {
#pragma unroll
        for (int j = 0; j < NP_; ++j) {
            float v = acc[j] + b3[j];
            latent[wid * NP_ + j] = v;
            out[wid * NP_ + j]    = 1.f / (1.f + expf(-v));
        }
    }
}

// ---------------------------------------------------------------------------
extern "C" void kernel_launch(void* const* d_in, const int* in_sizes, int n_in,
                              void* d_out, int out_size, void* d_ws, size_t ws_size,
                              hipStream_t stream)
{
    const float* motion_z = (const float*)d_in[0];
    const int*   tasks    = (const int*)d_in[1];
    const int*   tmask    = (const int*)d_in[2];
    const int*   pids     = (const int*)d_in[3];
    const float* phenos   = (const float*)d_in[4];
    const int*   pmask    = (const int*)d_in[5];
    const float* W1 = (const float*)d_in[6];
    const float* b1 = (const float*)d_in[7];
    const float* W2 = (const float*)d_in[8];
    const float* b2 = (const float*)d_in[9];
    const float* W3 = (const float*)d_in[10];
    const float* b3 = (const float*)d_in[11];

    char* ws = (char*)d_ws;
    float* pt_sum = (float*)(ws + OFF_PTSUM);   // becomes fingerprint in place
    float* pt_cnt = (float*)(ws + OFF_PTCNT);
    int*   first  = (int*)  (ws + OFF_FIRST);
    float* tmean  = (float*)(ws + OFF_TMEAN);
    float* h1     = (float*)(ws + OFF_H1);
    float* h2     = (float*)(ws + OFF_H2);

    float* out    = (float*)d_out;              // [0:18000)  sigmoid
    float* uni    = out + P_ * NP_;             // [18000:36000) uni_phenos
    float* latent = out + 2 * P_ * NP_;         // [36000:54000) pheno_latent

    hipMemsetAsync(pt_sum, 0,    SZ_PTSUM, stream);
    hipMemsetAsync(pt_cnt, 0,    SZ_PTCNT, stream);
    hipMemsetAsync(first,  0x7f, SZ_FIRST, stream);  // "infinity" > N

    scatter_pt<<<N_SAMP / 4, 256, 0, stream>>>(motion_z, tasks, tmask, pids,
                                               pmask, pt_sum, pt_cnt, first);
    task_mean_k<<<4, 256, 0, stream>>>(pt_sum, pt_cnt, tmean);
    finalize_fp<<<(16000 * D_) / 256, 256, 0, stream>>>(pt_sum, pt_cnt, tmean);
    gather_phenos<<<(P_ * NP_ + 255) / 256, 256, 0, stream>>>(first, phenos, uni);

    // fingerprint[2000,1024] @ W1[1024,2048] -> h1 (relu)
    gemm_bias_act<<<dim3(H_ / BN, (P_ + BM - 1) / BM), 256, 0, stream>>>(
        pt_sum, W1, b1, h1, P_, H_, T_ * D_, 1);
    // h1 @ W2[2048,2048] -> h2 (relu)
    gemm_bias_act<<<dim3(H_ / BN, (P_ + BM - 1) / BM), 256, 0, stream>>>(
        h1, W2, b2, h2, P_, H_, H_, 1);
    // head: h2 @ W3 + b3 -> latent, sigmoid -> out
    out_head<<<P_ / 4, 256, 0, stream>>>(h2, W3, b3, out, latent);
}

// Round 2
// 611.195 us; speedup vs baseline: 1.2020x; 1.2020x over previous
//
#include <hip/hip_runtime.h>
#include <math.h>

// Problem constants (from reference)
#define N_SAMP 200000
#define D_     128
#define T_     8
#define P_     2000
#define NP_    9
#define H_     2048
#define MPAD   2048          // padded M for guard-free MFMA GEMM

// ---------------------------------------------------------------------------
// Workspace layout (bytes, 256-aligned). h2 overlays {fphi,fplo,w1thi,w1tlo}
// (16,777,216 B exactly), which are dead after GEMM1. Total ~58.6 MB.
// ---------------------------------------------------------------------------
#define OFF_PTSUM   0
#define SZ_PTSUM    (16000*128*4)      // 8,192,000
#define OFF_PTCNT   8192000
#define SZ_PTCNT    (16000*4)
#define OFF_FIRST   8256000
#define SZ_FIRST    (P_*4)
#define OFF_TMEAN   8264192
#define OFF_FPHI    8268288            // 2048*1024*2 = 4,194,304
#define OFF_FPLO    12462592
#define OFF_W1THI   16656896
#define OFF_W1TLO   20851200
#define OFF_H1HI    25045504           // 2048*2048*2 = 8,388,608
#define OFF_H1LO    33434112
#define OFF_W2THI   41822720
#define OFF_W2TLO   50211328
#define OFF_H2      OFF_FPHI           // overlay, 2048*2048*4 = 16,777,216

typedef __attribute__((ext_vector_type(8))) short bf16x8;
typedef __attribute__((ext_vector_type(4))) float f32x4;

// bf16 split helpers (bit ops, RNE)
__device__ __forceinline__ unsigned f2bf_rne(float x) {
    unsigned b = __float_as_uint(x);
    return (b + 0x7fffu + ((b >> 16) & 1u)) >> 16;
}
__device__ __forceinline__ float bf2f(unsigned u) {
    return __uint_as_float(u << 16);
}

// ---------------------------------------------------------------------------
// Kernel 1: scatter-reduce. One wave per sample row; invalid rows early-out.
// ---------------------------------------------------------------------------
__global__ __launch_bounds__(256) void scatter_pt(
    const float* __restrict__ motion_z, const int* __restrict__ tasks,
    const int* __restrict__ tmask, const int* __restrict__ pids,
    const int* __restrict__ pmask, float* __restrict__ pt_sum,
    float* __restrict__ pt_cnt, int* __restrict__ first)
{
    int wid  = (blockIdx.x * blockDim.x + threadIdx.x) >> 6;
    int lane = threadIdx.x & 63;
    if (wid >= N_SAMP) return;
    if (tmask[wid] != 1 || pmask[wid] != 1) return;
    int seg = pids[wid] * T_ + tasks[wid];
    if (lane == 0) {
        atomicAdd(&pt_cnt[seg], 1.0f);
        atomicMin(&first[pids[wid]], wid);
    }
    float2 v = *(const float2*)&motion_z[(size_t)wid * D_ + lane * 2];
    atomicAdd(&pt_sum[seg * D_ + lane * 2 + 0], v.x);
    atomicAdd(&pt_sum[seg * D_ + lane * 2 + 1], v.y);
}

// ---------------------------------------------------------------------------
// Kernel 2: task_mean[t][d] over patients (pt_sum is L2-resident).
// ---------------------------------------------------------------------------
__global__ __launch_bounds__(256) void task_mean_k(
    const float* __restrict__ pt_sum, const float* __restrict__ pt_cnt,
    float* __restrict__ tmean)
{
    int tid = blockIdx.x * blockDim.x + threadIdx.x;
    if (tid >= T_ * D_) return;
    int t = tid >> 7, d = tid & 127;
    float s = 0.f, c = 0.f;
    for (int p = 0; p < P_; ++p) {
        s += pt_sum[(size_t)(p * T_ + t) * D_ + d];
        c += pt_cnt[p * T_ + t];
    }
    tmean[tid] = s / fmaxf(c, 1.0f);
}

// ---------------------------------------------------------------------------
// Kernel 3: finalize fingerprint -> bf16 hi/lo, rows padded to 2048 (zeros).
// fphi/fplo layout [2048][1024] row-major (A operand of GEMM1).
// ---------------------------------------------------------------------------
__global__ __launch_bounds__(256) void finalize_split(
    const float* __restrict__ pt_sum, const float* __restrict__ pt_cnt,
    const float* __restrict__ tmean,
    unsigned short* __restrict__ fphi, unsigned short* __restrict__ fplo)
{
    int e = blockIdx.x * blockDim.x + threadIdx.x;   // over 2048*1024
    int p = e >> 10, col = e & 1023;
    float v = 0.f;
    if (p < P_) {
        int seg = p * T_ + (col >> 7);
        float c = pt_cnt[seg];
        v = (c > 0.f) ? pt_sum[e] / c : tmean[col];
    }
    unsigned hi = f2bf_rne(v);
    float lo = v - bf2f(hi);
    fphi[e] = (unsigned short)hi;
    fplo[e] = (unsigned short)f2bf_rne(lo);
}

// ---------------------------------------------------------------------------
// Kernel 4: gather first-valid pheno row per patient.
// ---------------------------------------------------------------------------
__global__ void gather_phenos(const int* __restrict__ first,
                              const float* __restrict__ phenos,
                              float* __restrict__ up)
{
    int e = blockIdx.x * blockDim.x + threadIdx.x;
    if (e >= P_ * NP_) return;
    int p = e / NP_, j = e - p * NP_;
    int idx = first[p];
    if (idx > N_SAMP - 1) idx = N_SAMP - 1;
    up[e] = phenos[(size_t)idx * NP_ + j];
}

// ---------------------------------------------------------------------------
// Kernel 5: W [K][N] f32 -> Wt hi/lo bf16 [N][K] (transpose + split).
// ---------------------------------------------------------------------------
__global__ __launch_bounds__(256) void conv_w_t(
    const float* __restrict__ W, unsigned short* __restrict__ Whi,
    unsigned short* __restrict__ Wlo, int K, int N)
{
    __shared__ float tile[32][36];
    int k0 = blockIdx.y * 32, n0 = blockIdx.x * 32;
    int r = threadIdx.x >> 3, c4 = (threadIdx.x & 7) * 4;
    float4 v = *(const float4*)&W[(size_t)(k0 + r) * N + n0 + c4];
    tile[r][c4 + 0] = v.x; tile[r][c4 + 1] = v.y;
    tile[r][c4 + 2] = v.z; tile[r][c4 + 3] = v.w;
    __syncthreads();
    unsigned short hi[4], lo[4];
#pragma unroll
    for (int q = 0; q < 4; ++q) {
        float x = tile[c4 + q][r];
        unsigned h = f2bf_rne(x);
        hi[q] = (unsigned short)h;
        lo[q] = (unsigned short)f2bf_rne(x - bf2f(h));
    }
    size_t o = (size_t)(n0 + r) * K + k0 + c4;
    *(ushort4*)&Whi[o] = make_ushort4(hi[0], hi[1], hi[2], hi[3]);
    *(ushort4*)&Wlo[o] = make_ushort4(lo[0], lo[1], lo[2], lo[3]);
}

// ---------------------------------------------------------------------------
// Kernel 6: MFMA split-precision GEMM. C = relu(A@B + bias).
// A: hi/lo bf16 [MPAD][K] row-major. B: hi/lo bf16 [N][K] (pre-transposed).
// 128x128x32 tile, 4 waves (64x64 each), double-buffered reg-staged LDS,
// 80B padded LDS rows (bank-start stride 20 mod 32 -> 2-way, free).
// OUTF32=0: emit hi/lo bf16 (feeds next GEMM). OUTF32=1: emit f32.
// ---------------------------------------------------------------------------
#define LROW 80
template<int OUTF32>
__global__ __launch_bounds__(256, 1) void gemm_split(
    const unsigned short* __restrict__ Ahi, const unsigned short* __restrict__ Alo,
    const unsigned short* __restrict__ Bhi, const unsigned short* __restrict__ Blo,
    const float* __restrict__ bias,
    float* __restrict__ Cf, unsigned short* __restrict__ Chi,
    unsigned short* __restrict__ Clo, int K)
{
    __shared__ __align__(16) char lds[2][4][128 * LROW];   // [buf][Ahi,Alo,Bhi,Blo]
    int tid  = threadIdx.x;
    int lane = tid & 63, w = tid >> 6;
    int wr = w >> 1, wc = w & 1;
    int row0 = blockIdx.y * 128, col0 = blockIdx.x * 128;

    // staging: thread covers row sr, bytes [sh*16, sh*16+32) of the 64B k-row
    int sr = tid >> 1;
    int sh = (tid & 1) * 2;
    const size_t aB = ((size_t)(row0 + sr) * K) * 2;   // byte offsets
    const size_t bB = ((size_t)(col0 + sr) * K) * 2;

    float4 rA[2][2], rB[2][2];                          // [hi/lo][seg]

    auto LOAD = [&](int kt) {
        size_t k0b = (size_t)kt * 64;                   // 32 bf16 = 64B
        const char* pAhi = (const char*)Ahi + aB + k0b + sh * 16;
        const char* pAlo = (const char*)Alo + aB + k0b + sh * 16;
        const char* pBhi = (const char*)Bhi + bB + k0b + sh * 16;
        const char* pBlo = (const char*)Blo + bB + k0b + sh * 16;
        rA[0][0] = *(const float4*)(pAhi);  rA[0][1] = *(const float4*)(pAhi + 16);
        rA[1][0] = *(const float4*)(pAlo);  rA[1][1] = *(const float4*)(pAlo + 16);
        rB[0][0] = *(const float4*)(pBhi);  rB[0][1] = *(const float4*)(pBhi + 16);
        rB[1][0] = *(const float4*)(pBlo);  rB[1][1] = *(const float4*)(pBlo + 16);
    };
    auto WRITE = [&](int buf) {
        int o = sr * LROW + sh * 16;
        *(float4*)&lds[buf][0][o]      = rA[0][0];
        *(float4*)&lds[buf][0][o + 16] = rA[0][1];
        *(float4*)&lds[buf][1][o]      = rA[1][0];
        *(float4*)&lds[buf][1][o + 16] = rA[1][1];
        *(float4*)&lds[buf][2][o]      = rB[0][0];
        *(float4*)&lds[buf][2][o + 16] = rB[0][1];
        *(float4*)&lds[buf][3][o]      = rB[1][0];
        *(float4*)&lds[buf][3][o + 16] = rB[1][1];
    };

    f32x4 acc[4][4] = {};
    int nt = K / 32;
    LOAD(0); WRITE(0); __syncthreads();
    int cur = 0;
    int ra = (wr * 64 + (lane & 15)) * LROW + (lane >> 4) * 16;
    int rb = (wc * 64 + (lane & 15)) * LROW + (lane >> 4) * 16;

    for (int t = 0; t < nt; ++t) {
        if (t + 1 < nt) LOAD(t + 1);
        bf16x8 ah[4], al[4], bh[4], bl[4];
#pragma unroll
        for (int i = 0; i < 4; ++i) {
            ah[i] = *(const bf16x8*)&lds[cur][0][ra + i * 16 * LROW];
            al[i] = *(const bf16x8*)&lds[cur][1][ra + i * 16 * LROW];
        }
#pragma unroll
        for (int j = 0; j < 4; ++j) {
            bh[j] = *(const bf16x8*)&lds[cur][2][rb + j * 16 * LROW];
            bl[j] = *(const bf16x8*)&lds[cur][3][rb + j * 16 * LROW];
        }
#pragma unroll
        for (int i = 0; i < 4; ++i)
#pragma unroll
            for (int j = 0; j < 4; ++j) {
                acc[i][j] = __builtin_amdgcn_mfma_f32_16x16x32_bf16(ah[i], bh[j], acc[i][j], 0, 0, 0);
                acc[i][j] = __builtin_amdgcn_mfma_f32_16x16x32_bf16(ah[i], bl[j], acc[i][j], 0, 0, 0);
                acc[i][j] = __builtin_amdgcn_mfma_f32_16x16x32_bf16(al[i], bh[j], acc[i][j], 0, 0, 0);
            }
        if (t + 1 < nt) WRITE(cur ^ 1);
        __syncthreads();
        cur ^= 1;
    }

    // Epilogue: C/D layout col=lane&15, row=(lane>>4)*4+reg  [m89-verified]
#pragma unroll
    for (int i = 0; i < 4; ++i) {
        int r = row0 + wr * 64 + i * 16 + (lane >> 4) * 4;
#pragma unroll
        for (int j = 0; j < 4; ++j) {
            int c = col0 + wc * 64 + j * 16 + (lane & 15);
            float bv = bias[c];
#pragma unroll
            for (int q = 0; q < 4; ++q) {
                float x = fmaxf(acc[i][j][q] + bv, 0.f);
                size_t o = (size_t)(r + q) * H_ + c;
                if (OUTF32) {
                    Cf[o] = x;
                } else {
                    unsigned hb = f2bf_rne(x);
                    Chi[o] = (unsigned short)hb;
                    Clo[o] = (unsigned short)f2bf_rne(x - bf2f(hb));
                }
            }
        }
    }
}

// ---------------------------------------------------------------------------
// Kernel 7: head GEMM [2000,2048]@[2048,9] + b3 -> latent; out = sigmoid.
// ---------------------------------------------------------------------------
__global__ __launch_bounds__(256) void out_head(
    const float* __restrict__ h2, const float* __restrict__ W3,
    const float* __restrict__ b3, float* __restrict__ out,
    float* __restrict__ latent)
{
    int wid  = (blockIdx.x * blockDim.x + threadIdx.x) >> 6;
    int lane = threadIdx.x & 63;
    if (wid >= P_) return;
    const float* hrow = h2 + (size_t)wid * H_;
    float acc[NP_] = {};
    for (int k = lane; k < H_; k += 64) {
        float h = hrow[k];
        const float* wr = W3 + (size_t)k * NP_;
#pragma unroll
        for (int j = 0; j < NP_; ++j) acc[j] = fmaf(h, wr[j], acc[j]);
    }
#pragma unroll
    for (int off = 32; off > 0; off >>= 1)
#pragma unroll
        for (int j = 0; j < NP_; ++j) acc[j] += __shfl_down(acc[j], off);
    if (lane == 0) {
#pragma unroll
        for (int j = 0; j < NP_; ++j) {
            float v = acc[j] + b3[j];
            latent[wid * NP_ + j] = v;
            out[wid * NP_ + j]    = 1.f / (1.f + expf(-v));
        }
    }
}

// ---------------------------------------------------------------------------
extern "C" void kernel_launch(void* const* d_in, const int* in_sizes, int n_in,
                              void* d_out, int out_size, void* d_ws, size_t ws_size,
                              hipStream_t stream)
{
    const float* motion_z = (const float*)d_in[0];
    const int*   tasks    = (const int*)d_in[1];
    const int*   tmask    = (const int*)d_in[2];
    const int*   pids     = (const int*)d_in[3];
    const float* phenos   = (const float*)d_in[4];
    const int*   pmask    = (const int*)d_in[5];
    const float* W1 = (const float*)d_in[6];
    const float* b1 = (const float*)d_in[7];
    const float* W2 = (const float*)d_in[8];
    const float* b2 = (const float*)d_in[9];
    const float* W3 = (const float*)d_in[10];
    const float* b3 = (const float*)d_in[11];

    char* ws = (char*)d_ws;
    float*          pt_sum = (float*)(ws + OFF_PTSUM);
    float*          pt_cnt = (float*)(ws + OFF_PTCNT);
    int*            first  = (int*)  (ws + OFF_FIRST);
    float*          tmean  = (float*)(ws + OFF_TMEAN);
    unsigned short* fphi   = (unsigned short*)(ws + OFF_FPHI);
    unsigned short* fplo   = (unsigned short*)(ws + OFF_FPLO);
    unsigned short* w1thi  = (unsigned short*)(ws + OFF_W1THI);
    unsigned short* w1tlo  = (unsigned short*)(ws + OFF_W1TLO);
    unsigned short* h1hi   = (unsigned short*)(ws + OFF_H1HI);
    unsigned short* h1lo   = (unsigned short*)(ws + OFF_H1LO);
    unsigned short* w2thi  = (unsigned short*)(ws + OFF_W2THI);
    unsigned short* w2tlo  = (unsigned short*)(ws + OFF_W2TLO);
    float*          h2     = (float*)(ws + OFF_H2);      // overlays fphi..w1tlo

    float* out    = (float*)d_out;
    float* uni    = out + P_ * NP_;
    float* latent = out + 2 * P_ * NP_;

    hipMemsetAsync(pt_sum, 0,    SZ_PTSUM, stream);
    hipMemsetAsync(pt_cnt, 0,    SZ_PTCNT, stream);
    hipMemsetAsync(first,  0x7f, SZ_FIRST, stream);

    scatter_pt<<<N_SAMP / 4, 256, 0, stream>>>(motion_z, tasks, tmask, pids,
                                               pmask, pt_sum, pt_cnt, first);
    task_mean_k<<<4, 256, 0, stream>>>(pt_sum, pt_cnt, tmean);
    finalize_split<<<(MPAD * 1024) / 256, 256, 0, stream>>>(
        pt_sum, pt_cnt, tmean, fphi, fplo);
    gather_phenos<<<(P_ * NP_ + 255) / 256, 256, 0, stream>>>(first, phenos, uni);

    // Weight transpose+split: W1 [1024,2048] -> [2048,1024]; W2 [2048,2048]
    conv_w_t<<<dim3(H_ / 32, 1024 / 32), 256, 0, stream>>>(W1, w1thi, w1tlo, 1024, H_);
    conv_w_t<<<dim3(H_ / 32, H_ / 32),   256, 0, stream>>>(W2, w2thi, w2tlo, H_, H_);

    // GEMM1: fingerprint[2048,1024] @ W1 -> h1 (relu, bf16 hi/lo out)
    gemm_split<0><<<dim3(H_ / 128, MPAD / 128), 256, 0, stream>>>(
        fphi, fplo, w1thi, w1tlo, b1, nullptr, h1hi, h1lo, 1024);
    // GEMM2: h1[2048,2048] @ W2 -> h2 (relu, f32 out)
    gemm_split<1><<<dim3(H_ / 128, MPAD / 128), 256, 0, stream>>>(
        h1hi, h1lo, w2thi, w2tlo, b2, h2, nullptr, nullptr, H_);

    out_head<<<P_ / 4, 256, 0, stream>>>(h2, W3, b3, out, latent);
}

// Round 3
// 447.777 us; speedup vs baseline: 1.6406x; 1.3650x over previous
//
#include <hip/hip_runtime.h>
#include <math.h>

// Problem constants (from reference)
#define N_SAMP 200000
#define D_     128
#define T_     8
#define P_     2000
#define NP_    9
#define H_     2048
#define MPAD   2048          // padded M for guard-free MFMA GEMM

// ---------------------------------------------------------------------------
// Workspace layout (bytes, 256-aligned). h2 overlays {fphi,fplo,w1thi,w1tlo}
// (dead after GEMM1). tsum/tcnt overlay h1hi (dead until GEMM1 writes it).
// ---------------------------------------------------------------------------
#define OFF_PTSUM   0
#define SZ_PTSUM    (16000*128*4)      // 8,192,000
#define OFF_PTCNT   8192000
#define SZ_PTCNT    (16000*4)
#define OFF_FIRST   8256000
#define SZ_FIRST    (P_*4)
#define OFF_TMEAN   8264192
#define OFF_FPHI    8268288            // 2048*1024*2 = 4,194,304
#define OFF_FPLO    12462592
#define OFF_W1THI   16656896
#define OFF_W1TLO   20851200
#define OFF_H1HI    25045504           // 2048*2048*2 = 8,388,608
#define OFF_H1LO    33434112
#define OFF_W2THI   41822720
#define OFF_W2TLO   50211328
#define OFF_H2      OFF_FPHI           // overlay (16,777,216 B exactly)
#define OFF_TSUM    OFF_H1HI           // overlay: 1024 f32 partial sums
#define OFF_TCNT    (OFF_H1HI + 4096)  // 8 f32 task counts

typedef __attribute__((ext_vector_type(8))) short bf16x8;
typedef __attribute__((ext_vector_type(4))) float f32x4;

// bf16 split helpers (bit ops, RNE)
__device__ __forceinline__ unsigned f2bf_rne(float x) {
    unsigned b = __float_as_uint(x);
    return (b + 0x7fffu + ((b >> 16) & 1u)) >> 16;
}
__device__ __forceinline__ float bf2f(unsigned u) {
    return __uint_as_float(u << 16);
}

// async global->LDS, 16B/lane: LDS dest = wave-uniform base + lane*16 [m97/m104]
__device__ __forceinline__ void gload16(const void* g, void* l) {
    __builtin_amdgcn_global_load_lds(
        (const __attribute__((address_space(1))) unsigned int*)g,
        (__attribute__((address_space(3))) unsigned int*)l, 16, 0, 0);
}

// ---------------------------------------------------------------------------
// Kernel 1: scatter-reduce, grid-stride waves (2048 blocks x 4 waves).
// ---------------------------------------------------------------------------
__global__ __launch_bounds__(256) void scatter_pt(
    const float* __restrict__ motion_z, const int* __restrict__ tasks,
    const int* __restrict__ tmask, const int* __restrict__ pids,
    const int* __restrict__ pmask, float* __restrict__ pt_sum,
    float* __restrict__ pt_cnt, int* __restrict__ first)
{
    int wid0 = (blockIdx.x * blockDim.x + threadIdx.x) >> 6;
    int lane = threadIdx.x & 63;
    int nw   = (gridDim.x * blockDim.x) >> 6;
    for (int wid = wid0; wid < N_SAMP; wid += nw) {
        if (tmask[wid] != 1 || pmask[wid] != 1) continue;
        int seg = pids[wid] * T_ + tasks[wid];
        if (lane == 0) {
            atomicAdd(&pt_cnt[seg], 1.0f);
            atomicMin(&first[pids[wid]], wid);
        }
        float2 v = *(const float2*)&motion_z[(size_t)wid * D_ + lane * 2];
        atomicAdd(&pt_sum[seg * D_ + lane * 2 + 0], v.x);
        atomicAdd(&pt_sum[seg * D_ + lane * 2 + 1], v.y);
    }
}

// ---------------------------------------------------------------------------
// Kernel 2a: streaming partial reduce over patients for task mean.
// 125 blocks x 16 patients each; coalesced float4 reads; atomics into tsum.
// ---------------------------------------------------------------------------
__global__ __launch_bounds__(256) void tsum_partial(
    const float* __restrict__ pt_sum, const float* __restrict__ pt_cnt,
    float* __restrict__ tsum, float* __restrict__ tcnt)
{
    int p0 = blockIdx.x * 16;
    int tid = threadIdx.x;
    float4 acc = make_float4(0.f, 0.f, 0.f, 0.f);
    for (int pl = 0; pl < 16; ++pl) {
        float4 v = *(const float4*)&pt_sum[(size_t)(p0 + pl) * 1024 + tid * 4];
        acc.x += v.x; acc.y += v.y; acc.z += v.z; acc.w += v.w;
    }
    atomicAdd(&tsum[tid * 4 + 0], acc.x);
    atomicAdd(&tsum[tid * 4 + 1], acc.y);
    atomicAdd(&tsum[tid * 4 + 2], acc.z);
    atomicAdd(&tsum[tid * 4 + 3], acc.w);
    if (tid < 128) {
        int p = p0 + (tid >> 3), t = tid & 7;
        atomicAdd(&tcnt[t], pt_cnt[p * 8 + t]);
    }
}

// Kernel 2b: tmean = tsum / max(tcnt,1)   (1024 elems)
__global__ __launch_bounds__(256) void tmean_div(
    const float* __restrict__ tsum, const float* __restrict__ tcnt,
    float* __restrict__ tmean)
{
    int e = blockIdx.x * 256 + threadIdx.x;
    if (e >= 1024) return;
    tmean[e] = tsum[e] / fmaxf(tcnt[e >> 7], 1.0f);
}

// ---------------------------------------------------------------------------
// Kernel 3: finalize fingerprint -> bf16 hi/lo, rows padded to 2048 (zeros).
// ---------------------------------------------------------------------------
__global__ __launch_bounds__(256) void finalize_split(
    const float* __restrict__ pt_sum, const float* __restrict__ pt_cnt,
    const float* __restrict__ tmean,
    unsigned short* __restrict__ fphi, unsigned short* __restrict__ fplo)
{
    int e = blockIdx.x * blockDim.x + threadIdx.x;   // over 2048*1024
    int p = e >> 10, col = e & 1023;
    float v = 0.f;
    if (p < P_) {
        int seg = p * T_ + (col >> 7);
        float c = pt_cnt[seg];
        v = (c > 0.f) ? pt_sum[e] / c : tmean[col];
    }
    unsigned hi = f2bf_rne(v);
    float lo = v - bf2f(hi);
    fphi[e] = (unsigned short)hi;
    fplo[e] = (unsigned short)f2bf_rne(lo);
}

// ---------------------------------------------------------------------------
// Kernel 4: gather first-valid pheno row per patient.
// ---------------------------------------------------------------------------
__global__ void gather_phenos(const int* __restrict__ first,
                              const float* __restrict__ phenos,
                              float* __restrict__ up)
{
    int e = blockIdx.x * blockDim.x + threadIdx.x;
    if (e >= P_ * NP_) return;
    int p = e / NP_, j = e - p * NP_;
    int idx = first[p];
    if (idx > N_SAMP - 1) idx = N_SAMP - 1;
    up[e] = phenos[(size_t)idx * NP_ + j];
}

// ---------------------------------------------------------------------------
// Kernel 5: W [K][N] f32 -> Wt hi/lo bf16 [N][K] (transpose + split).
// ---------------------------------------------------------------------------
__global__ __launch_bounds__(256) void conv_w_t(
    const float* __restrict__ W, unsigned short* __restrict__ Whi,
    unsigned short* __restrict__ Wlo, int K, int N)
{
    __shared__ float tile[32][36];
    int k0 = blockIdx.y * 32, n0 = blockIdx.x * 32;
    int r = threadIdx.x >> 3, c4 = (threadIdx.x & 7) * 4;
    float4 v = *(const float4*)&W[(size_t)(k0 + r) * N + n0 + c4];
    tile[r][c4 + 0] = v.x; tile[r][c4 + 1] = v.y;
    tile[r][c4 + 2] = v.z; tile[r][c4 + 3] = v.w;
    __syncthreads();
    unsigned short hi[4], lo[4];
#pragma unroll
    for (int q = 0; q < 4; ++q) {
        float x = tile[c4 + q][r];
        unsigned h = f2bf_rne(x);
        hi[q] = (unsigned short)h;
        lo[q] = (unsigned short)f2bf_rne(x - bf2f(h));
    }
    size_t o = (size_t)(n0 + r) * K + k0 + c4;
    *(ushort4*)&Whi[o] = make_ushort4(hi[0], hi[1], hi[2], hi[3]);
    *(ushort4*)&Wlo[o] = make_ushort4(lo[0], lo[1], lo[2], lo[3]);
}

// ---------------------------------------------------------------------------
// Kernel 6: MFMA split-precision GEMM, fragment-ordered LDS + global_load_lds.
// A: hi/lo bf16 [MPAD][K] row-major. B: hi/lo bf16 [N][K] (pre-transposed).
// 128x128x32 tile, 4 waves (64x64 each), double-buffered 64KB LDS.
// LDS layout: [buf][piece(Ahi,Alo,Bhi,Blo)][m-tile 0..7][lane*16B] -- every
// ds_read_b128 is a contiguous 1KB wave read (conflict-free by construction);
// every stage is one global_load_lds_dwordx4 (uniform LDS base + lane*16).
// Fragment map (verified R1-pass): lane l holds X[row=l&15][k0+(l>>4)*8+0..7].
// ---------------------------------------------------------------------------
template<int OUTF32>
__global__ __launch_bounds__(256, 1) void gemm_split(
    const unsigned short* __restrict__ Ahi, const unsigned short* __restrict__ Alo,
    const unsigned short* __restrict__ Bhi, const unsigned short* __restrict__ Blo,
    const float* __restrict__ bias,
    float* __restrict__ Cf, unsigned short* __restrict__ Chi,
    unsigned short* __restrict__ Clo, int K)
{
    __shared__ __align__(16) char lds[2][4][8192];   // 64 KiB
    int tid  = threadIdx.x;
    int lane = tid & 63, w = tid >> 6;
    int wr = w >> 1, wc = w & 1;
    int row0 = blockIdx.y * 128, col0 = blockIdx.x * 128;

    // per-lane fragment source coordinates
    int fr = lane & 15;          // row within 16-row tile
    int fk = (lane >> 4) * 8;    // k-chunk

    const unsigned short* srcs[4] = {Ahi, Alo, Bhi, Blo};
    int base0[4] = {row0, row0, col0, col0};

    auto STAGE = [&](int buf, int t) {
        int k0 = t * 32;
#pragma unroll
        for (int pc = 0; pc < 4; ++pc) {
#pragma unroll
            for (int rep = 0; rep < 2; ++rep) {
                int tile = rep * 4 + w;                       // wave-uniform
                const unsigned short* g =
                    srcs[pc] + (size_t)(base0[pc] + tile * 16 + fr) * K + k0 + fk;
                gload16(g, &lds[buf][pc][tile * 1024]);       // uniform base
            }
        }
    };

    f32x4 acc[4][4] = {};
    int nt = K / 32;
    STAGE(0, 0);
    __syncthreads();
    int cur = 0;
    int lo16 = lane * 16;

    for (int t = 0; t < nt; ++t) {
        if (t + 1 < nt) STAGE(cur ^ 1, t + 1);
        bf16x8 ah[4], al[4], bh[4], bl[4];
#pragma unroll
        for (int i = 0; i < 4; ++i) {
            ah[i] = *(const bf16x8*)&lds[cur][0][(wr * 4 + i) * 1024 + lo16];
            al[i] = *(const bf16x8*)&lds[cur][1][(wr * 4 + i) * 1024 + lo16];
        }
#pragma unroll
        for (int j = 0; j < 4; ++j) {
            bh[j] = *(const bf16x8*)&lds[cur][2][(wc * 4 + j) * 1024 + lo16];
            bl[j] = *(const bf16x8*)&lds[cur][3][(wc * 4 + j) * 1024 + lo16];
        }
#pragma unroll
        for (int i = 0; i < 4; ++i)
#pragma unroll
            for (int j = 0; j < 4; ++j) {
                acc[i][j] = __builtin_amdgcn_mfma_f32_16x16x32_bf16(ah[i], bh[j], acc[i][j], 0, 0, 0);
                acc[i][j] = __builtin_amdgcn_mfma_f32_16x16x32_bf16(ah[i], bl[j], acc[i][j], 0, 0, 0);
                acc[i][j] = __builtin_amdgcn_mfma_f32_16x16x32_bf16(al[i], bh[j], acc[i][j], 0, 0, 0);
            }
        __syncthreads();     // drains staged loads (vmcnt0) + frees cur for next stage
        cur ^= 1;
    }

    // Epilogue: C/D layout col=lane&15, row=(lane>>4)*4+reg  [m89-verified]
#pragma unroll
    for (int i = 0; i < 4; ++i) {
        int r = row0 + wr * 64 + i * 16 + (lane >> 4) * 4;
#pragma unroll
        for (int j = 0; j < 4; ++j) {
            int c = col0 + wc * 64 + j * 16 + (lane & 15);
            float bv = bias[c];
#pragma unroll
            for (int q = 0; q < 4; ++q) {
                float x = fmaxf(acc[i][j][q] + bv, 0.f);
                size_t o = (size_t)(r + q) * H_ + c;
                if (OUTF32) {
                    Cf[o] = x;
                } else {
                    unsigned hb = f2bf_rne(x);
                    Chi[o] = (unsigned short)hb;
                    Clo[o] = (unsigned short)f2bf_rne(x - bf2f(hb));
                }
            }
        }
    }
}

// ---------------------------------------------------------------------------
// Kernel 7: head GEMM [2000,2048]@[2048,9] + b3 -> latent; out = sigmoid.
// ---------------------------------------------------------------------------
__global__ __launch_bounds__(256) void out_head(
    const float* __restrict__ h2, const float* __restrict__ W3,
    const float* __restrict__ b3, float* __restrict__ out,
    float* __restrict__ latent)
{
    int wid  = (blockIdx.x * blockDim.x + threadIdx.x) >> 6;
    int lane = threadIdx.x & 63;
    if (wid >= P_) return;
    const float* hrow = h2 + (size_t)wid * H_;
    float acc[NP_] = {};
    for (int k = lane; k < H_; k += 64) {
        float h = hrow[k];
        const float* wr = W3 + (size_t)k * NP_;
#pragma unroll
        for (int j = 0; j < NP_; ++j) acc[j] = fmaf(h, wr[j], acc[j]);
    }
#pragma unroll
    for (int off = 32; off > 0; off >>= 1)
#pragma unroll
        for (int j = 0; j < NP_; ++j) acc[j] += __shfl_down(acc[j], off);
    if (lane == 0) {
#pragma unroll
        for (int j = 0; j < NP_; ++j) {
            float v = acc[j] + b3[j];
            latent[wid * NP_ + j] = v;
            out[wid * NP_ + j]    = 1.f / (1.f + expf(-v));
        }
    }
}

// ---------------------------------------------------------------------------
extern "C" void kernel_launch(void* const* d_in, const int* in_sizes, int n_in,
                              void* d_out, int out_size, void* d_ws, size_t ws_size,
                              hipStream_t stream)
{
    const float* motion_z = (const float*)d_in[0];
    const int*   tasks    = (const int*)d_in[1];
    const int*   tmask    = (const int*)d_in[2];
    const int*   pids     = (const int*)d_in[3];
    const float* phenos   = (const float*)d_in[4];
    const int*   pmask    = (const int*)d_in[5];
    const float* W1 = (const float*)d_in[6];
    const float* b1 = (const float*)d_in[7];
    const float* W2 = (const float*)d_in[8];
    const float* b2 = (const float*)d_in[9];
    const float* W3 = (const float*)d_in[10];
    const float* b3 = (const float*)d_in[11];

    char* ws = (char*)d_ws;
    float*          pt_sum = (float*)(ws + OFF_PTSUM);
    float*          pt_cnt = (float*)(ws + OFF_PTCNT);
    int*            first  = (int*)  (ws + OFF_FIRST);
    float*          tmean  = (float*)(ws + OFF_TMEAN);
    float*          tsum   = (float*)(ws + OFF_TSUM);
    float*          tcnt   = (float*)(ws + OFF_TCNT);
    unsigned short* fphi   = (unsigned short*)(ws + OFF_FPHI);
    unsigned short* fplo   = (unsigned short*)(ws + OFF_FPLO);
    unsigned short* w1thi  = (unsigned short*)(ws + OFF_W1THI);
    unsigned short* w1tlo  = (unsigned short*)(ws + OFF_W1TLO);
    unsigned short* h1hi   = (unsigned short*)(ws + OFF_H1HI);
    unsigned short* h1lo   = (unsigned short*)(ws + OFF_H1LO);
    unsigned short* w2thi  = (unsigned short*)(ws + OFF_W2THI);
    unsigned short* w2tlo  = (unsigned short*)(ws + OFF_W2TLO);
    float*          h2     = (float*)(ws + OFF_H2);

    float* out    = (float*)d_out;
    float* uni    = out + P_ * NP_;
    float* latent = out + 2 * P_ * NP_;

    hipMemsetAsync(pt_sum, 0,    SZ_PTSUM, stream);
    hipMemsetAsync(pt_cnt, 0,    SZ_PTCNT, stream);
    hipMemsetAsync(first,  0x7f, SZ_FIRST, stream);
    hipMemsetAsync(tsum,   0,    4096 + 256, stream);   // tsum + tcnt

    scatter_pt<<<2048, 256, 0, stream>>>(motion_z, tasks, tmask, pids,
                                         pmask, pt_sum, pt_cnt, first);
    tsum_partial<<<125, 256, 0, stream>>>(pt_sum, pt_cnt, tsum, tcnt);
    tmean_div<<<4, 256, 0, stream>>>(tsum, tcnt, tmean);
    finalize_split<<<(MPAD * 1024) / 256, 256, 0, stream>>>(
        pt_sum, pt_cnt, tmean, fphi, fplo);
    gather_phenos<<<(P_ * NP_ + 255) / 256, 256, 0, stream>>>(first, phenos, uni);

    conv_w_t<<<dim3(H_ / 32, 1024 / 32), 256, 0, stream>>>(W1, w1thi, w1tlo, 1024, H_);
    conv_w_t<<<dim3(H_ / 32, H_ / 32),   256, 0, stream>>>(W2, w2thi, w2tlo, H_, H_);

    // GEMM1: fingerprint[2048,1024] @ W1 -> h1 (relu, bf16 hi/lo out)
    gemm_split<0><<<dim3(H_ / 128, MPAD / 128), 256, 0, stream>>>(
        fphi, fplo, w1thi, w1tlo, b1, nullptr, h1hi, h1lo, 1024);
    // GEMM2: h1[2048,2048] @ W2 -> h2 (relu, f32 out)
    gemm_split<1><<<dim3(H_ / 128, MPAD / 128), 256, 0, stream>>>(
        h1hi, h1lo, w2thi, w2tlo, b2, h2, nullptr, nullptr, H_);

    out_head<<<P_ / 4, 256, 0, stream>>>(h2, W3, b3, out, latent);
}